// Round 3
// baseline (406.246 us; speedup 1.0000x reference)
//
#include <hip/hip_runtime.h>

// ---------------------------------------------------------------------------
// R_SCNN: two width-direction SCNN scans fused into one 127-step recurrence,
// executed with MFMA, then 4x bilinear upsample + global BN + sigmoid.
//
//   y_w = c_w + relu(M y_{w-1}),  z_w = y_w + relu(M z_{w-1}),  z_0 = y_0 = c_0
//   s[b,h,p] = dot(v, z_{127-p});  out = sigmoid(BN(upsample4(s)))
//
// Round-7: phase-staggered dual recurrence. R1/R2 evidence: step time is
// latency-serialization bound (8w=2010cy, 4w=2413cy; all pipes <25%) because
// the barrier locksteps all waves into the same burst phase (DS burst ->
// compute burst -> write burst). Now each block runs TWO independent (b,h)
// recurrences (waves 0-3 = group A, waves 4-7 = group B) offset by half a
// step: while A does read+MFMA, B does epilogue+write+prefetch. Two raw
// barriers per step; every interval each SIMD has one MFMA/DS wave + one
// VALU wave. Single-buffer carries (mid-step barrier separates RAW/WAR).
// z-history dropped: s-dot computed in-loop (f32) inside the EW phase; LDS
// 67KB -> 19KB. k_extract folded into the prologue (one launch saved).
// ---------------------------------------------------------------------------

typedef _Float16 f16x8 __attribute__((ext_vector_type(8)));
typedef _Float16 f16x4 __attribute__((ext_vector_type(4)));
typedef float    f32x4 __attribute__((ext_vector_type(4)));

// Raw workgroup barrier: drain LDS ops only; global (vmcnt) loads stay in
// flight across it.
static __device__ __forceinline__ void sync_lds() {
  asm volatile("s_waitcnt lgkmcnt(0)" ::: "memory");
  __builtin_amdgcn_s_barrier();
  asm volatile("" ::: "memory");
}

// quad_perm(0,0,2,2): lane 2k+1 receives lane 2k's value (VALU-speed, no LDS)
static __device__ __forceinline__ float dpp_even(float v) {
  int t = __builtin_bit_cast(int, v);
  t = __builtin_amdgcn_update_dpp(t, t, 0xA0, 0xF, 0xF, false);
  return __builtin_bit_cast(float, t);
}

// ---- kernel 1: fused double scan via MFMA, 2 staggered recurrences --------
struct GSM {
  _Float16 cy[256];        // y carry (f16)                [byte 0,    bank 0)
  _Float16 pad0[32];       // 64B: z carry starts bank 16 -> disjoint halves
  _Float16 cz[256];        // z carry (f16)                [byte 1088)
  _Float16 pad1[32];
  float    sp[128 * 16];   // z-dot partials [w][slot]     (8 KB)
};
struct SM { GSM g[2]; };

extern "C" __global__ void __launch_bounds__(512, 2)
k_scan(const float* __restrict__ p2, const float* __restrict__ convw,
       const float* __restrict__ conv1, float* __restrict__ sout,
       float* __restrict__ stats) {
  __shared__ SM sm;
  const int tid  = threadIdx.x;
  const int l    = tid & 63;
  const int wv   = tid >> 6;        // wave 0..7
  const int g    = wv >> 2;         // group 0 (A) / 1 (B)
  const int r    = wv & 3;          // wave-in-group 0..3
  const bool gA  = (g == 0);
  const int col  = l & 15;          // MFMA n / A-row-within-tile index
  const int quad = l >> 4;          // MFMA k-group / C-row-group index
  const int gh   = blockIdx.x * 2 + g;   // this group's (b,h) pair
  const int b    = gh >> 6;
  const int h    = gh & 63;

  if (blockIdx.x == 0 && tid == 0) { stats[0] = 0.f; stats[1] = 0.f; }

  GSM& S = sm.g[g];
  const bool isY   = (col == 0);    // lanes holding C column 0 (y results)
  const bool isZ   = (col == 1);    // lanes holding C column 1 (z results)
  const bool zlane = (l & 1);       // odd cols read the z stream as B

  // C/D rows owned by this lane: tiles 4r..4r+3, rows mrow[t]..mrow[t]+3
  int mrow[4];
#pragma unroll
  for (int t = 0; t < 4; ++t) mrow[t] = (r * 4 + t) * 16 + quad * 4;

  // A-fragments straight from conv_w center tap (k_extract folded in):
  // A[m = (r*4+t)*16+col][k = ch*32+quad*8+j] = convw[m*2304 + k*9 + 4]
  f16x8 A[4][8];
#pragma unroll
  for (int t = 0; t < 4; ++t) {
    const float* wrow = convw + (size_t)((r * 4 + t) * 16 + col) * 2304 + 4;
#pragma unroll
    for (int ch = 0; ch < 8; ++ch)
#pragma unroll
      for (int j = 0; j < 8; ++j)
        A[t][ch][j] = (_Float16)wrow[(ch * 32 + quad * 8 + j) * 9];
  }

  // p2_r[b][c][h][w]: channel c at pbase + c*8192 + w
  const float* pbase = p2 + (size_t)b * 2097152 + (size_t)h * 128;

  // Register union (saves 16 VGPR): c_vv = c_w for ODD steps on isY lanes,
  // conv1 weights on isZ lanes (disjoint lanes). c_ev = c_w for EVEN steps
  // (isY lanes only).
  float c_vv[4][4], c_ev[4][4];

  // init: w=0 state (z_0 = y_0 = c_0) into carries, sp[0], weight/prefetch
  {
    if (isY || isZ) {
      float c0[4][4];
#pragma unroll
      for (int t = 0; t < 4; ++t)
#pragma unroll
        for (int i = 0; i < 4; ++i)
          c0[t][i] = pbase[(size_t)(mrow[t] + i) * 8192];
      if (isY) {
#pragma unroll
        for (int t = 0; t < 4; ++t) {
          f16x4 p;
#pragma unroll
          for (int i = 0; i < 4; ++i) p[i] = (_Float16)c0[t][i];
          *(f16x4*)(S.cy + mrow[t]) = p;
          *(f16x4*)(S.cz + mrow[t]) = p;
        }
      } else {
        float p = 0.f;
#pragma unroll
        for (int t = 0; t < 4; ++t)
#pragma unroll
          for (int i = 0; i < 4; ++i) {
            c_vv[t][i] = conv1[mrow[t] + i];
            p += c_vv[t][i] * c0[t][i];
          }
        S.sp[0 * 16 + r * 4 + quad] = p;
      }
    }
    if (isY) {
#pragma unroll
      for (int t = 0; t < 4; ++t)
#pragma unroll
        for (int i = 0; i < 4; ++i) {
          c_vv[t][i] = pbase[(size_t)(mrow[t] + i) * 8192 + 1];
          c_ev[t][i] = pbase[(size_t)(mrow[t] + i) * 8192 + 2];
        }
    }
  }
  sync_lds();

  const _Float16* bsrc = (zlane ? S.cz : S.cy) + quad * 8;

  f32x4 acc0[4], acc1[4];   // MFMA accumulators, live across the mid barrier

  // RM: read carry, run MFMA chains (acc = M * [y|z])
#define RM()                                                                   \
  do {                                                                         \
    f16x8 B[8];                                                                \
    _Pragma("unroll")                                                          \
    for (int ch = 0; ch < 8; ++ch)                                             \
      B[ch] = *(const f16x8*)(bsrc + ch * 32);                                 \
    _Pragma("unroll")                                                          \
    for (int t = 0; t < 4; ++t) {                                              \
      acc0[t] = (f32x4){0.f, 0.f, 0.f, 0.f};                                   \
      acc1[t] = (f32x4){0.f, 0.f, 0.f, 0.f};                                   \
    }                                                                          \
    _Pragma("unroll")                                                          \
    for (int ch = 0; ch < 4; ++ch) {                                           \
      _Pragma("unroll")                                                        \
      for (int t = 0; t < 4; ++t) {                                            \
        acc0[t] = __builtin_amdgcn_mfma_f32_16x16x32_f16(A[t][ch],   B[ch],   acc0[t],0,0,0); \
        acc1[t] = __builtin_amdgcn_mfma_f32_16x16x32_f16(A[t][ch+4], B[ch+4], acc1[t],0,0,0); \
      }                                                                        \
    }                                                                          \
  } while (0)

  // EW: epilogue (y, z, dot partial) + carry writes + c prefetch for w+2
#define EW(W, C)                                                               \
  do {                                                                         \
    f32x4 acc[4];                                                              \
    _Pragma("unroll")                                                          \
    for (int t = 0; t < 4; ++t) acc[t] = acc0[t] + acc1[t];                    \
    f32x4 yf[4] = {};                                                          \
    if (isY) {                                                                 \
      _Pragma("unroll")                                                        \
      for (int t = 0; t < 4; ++t) {                                            \
        f16x4 yh;                                                              \
        _Pragma("unroll")                                                      \
        for (int i = 0; i < 4; ++i) {                                          \
          yf[t][i] = (C)[t][i] + fmaxf(acc[t][i], 0.f);                        \
          yh[i] = (_Float16)yf[t][i];                                          \
        }                                                                      \
        *(f16x4*)(S.cy + mrow[t]) = yh;                                        \
      }                                                                        \
      if ((W) + 2 < 128) {                                                     \
        _Pragma("unroll")                                                      \
        for (int t = 0; t < 4; ++t)                                            \
          _Pragma("unroll")                                                    \
          for (int i = 0; i < 4; ++i)                                          \
            (C)[t][i] = pbase[(size_t)(mrow[t] + i) * 8192 + (W) + 2];         \
      }                                                                        \
    }                                                                          \
    _Pragma("unroll")                                                          \
    for (int t = 0; t < 4; ++t)                                                \
      _Pragma("unroll")                                                        \
      for (int i = 0; i < 4; ++i)                                              \
        yf[t][i] = dpp_even(yf[t][i]);                                         \
    if (isZ) {                                                                 \
      float p = 0.f;                                                           \
      _Pragma("unroll")                                                        \
      for (int t = 0; t < 4; ++t) {                                            \
        f16x4 zo;                                                              \
        _Pragma("unroll")                                                      \
        for (int i = 0; i < 4; ++i) {                                          \
          float z = yf[t][i] + fmaxf(acc[t][i], 0.f);                          \
          zo[i] = (_Float16)z;                                                 \
          p += c_vv[t][i] * z;                                                 \
        }                                                                      \
        *(f16x4*)(S.cz + mrow[t]) = zo;                                        \
      }                                                                        \
      S.sp[(W) * 16 + r * 4 + quad] = p;                                       \
    }                                                                          \
  } while (0)

  // Staggered schedule: A leads by half a step. Per interval each SIMD has
  // one wave doing RM (DS+MFMA) and one doing EW (VALU+writes+prefetch).
#pragma unroll 1
  for (int w = 1; w < 127; w += 2) {
    if (gA) RM(); else if (w > 1) EW(w - 1, c_ev);   // w-1 even
    sync_lds();
    if (gA) EW(w, c_vv); else RM();                  // w odd
    sync_lds();
    if (gA) RM(); else EW(w, c_vv);
    sync_lds();
    if (gA) EW(w + 1, c_ev); else RM();              // w+1 even
    sync_lds();
  }
  // tail: w = 127 (odd)
  if (gA) RM(); else EW(126, c_ev);
  sync_lds();
  if (gA) EW(127, c_vv); else RM();
  sync_lds();
  if (!gA) EW(127, c_vv);
  sync_lds();
#undef RM
#undef EW

  // s[b,h,127-w] = dot(v, z_w): reduce 16 partials per (group, w)
  {
    const int rg   = tid >> 8;          // group
    const int w    = (tid >> 1) & 127;
    const int part = tid & 1;
    const float* q = sm.g[rg].sp + w * 16 + part * 8;
    float4 t0 = *(const float4*)q;
    float4 t1 = *(const float4*)(q + 4);
    float s = t0.x + t0.y + t0.z + t0.w + t1.x + t1.y + t1.z + t1.w;
    s += __shfl_xor(s, 1, 64);
    if (part == 0)
      sout[((blockIdx.x * 2 + rg) << 7) + (127 - w)] = s;
  }
}

// ---- bilinear 4x upsample (align_corners) of s: (2,64,128) -> (2,256,512) --
static __device__ __forceinline__ float bilin(const float* __restrict__ s,
                                              int idx) {
  int bb  = idx >> 17;
  int rem = idx & 131071;
  int ho  = rem >> 9;
  int wo  = rem & 511;
  const float SY = 63.0f / 255.0f, SX = 127.0f / 511.0f;
  float fy = (float)ho * SY;
  int y0 = (int)fy; int y1 = min(y0 + 1, 63); float wy = fy - (float)y0;
  float fx = (float)wo * SX;
  int x0 = (int)fx; int x1 = min(x0 + 1, 127); float wx = fx - (float)x0;
  const float* sb = s + bb * 8192;
  float cA = sb[y0 * 128 + x0] * (1.f - wy) + sb[y1 * 128 + x0] * wy;
  float cB = sb[y0 * 128 + x1] * (1.f - wy) + sb[y1 * 128 + x1] * wy;
  return cA * (1.f - wx) + cB * wx;
}

// ---- kernel 2: global sum / sumsq of upsampled field -----------------------
extern "C" __global__ void k_stats(const float* __restrict__ s,
                                   float* __restrict__ stats) {
  int tid  = threadIdx.x;
  int base = blockIdx.x * 1024 + tid;
  float sum = 0.f, ssq = 0.f;
#pragma unroll
  for (int i = 0; i < 4; ++i) {
    float u = bilin(s, base + i * 256);
    sum += u; ssq += u * u;
  }
#pragma unroll
  for (int off = 32; off > 0; off >>= 1) {
    sum += __shfl_xor(sum, off, 64);
    ssq += __shfl_xor(ssq, off, 64);
  }
  __shared__ float ls[4], lq[4];
  int wv = tid >> 6;
  if ((tid & 63) == 0) { ls[wv] = sum; lq[wv] = ssq; }
  __syncthreads();
  if (tid == 0) {
    atomicAdd(&stats[0], ls[0] + ls[1] + ls[2] + ls[3]);
    atomicAdd(&stats[1], lq[0] + lq[1] + lq[2] + lq[3]);
  }
}

// ---- kernel 3: normalize + sigmoid -----------------------------------------
extern "C" __global__ void k_norm(const float* __restrict__ s,
                                  const float* __restrict__ stats,
                                  const float* __restrict__ gamma,
                                  const float* __restrict__ beta,
                                  float* __restrict__ out) {
  int tid  = threadIdx.x;
  int base = blockIdx.x * 1024 + tid;
  const float invN = 1.f / 262144.f;
  float mean  = stats[0] * invN;
  float var   = stats[1] * invN - mean * mean;
  float scale = rsqrtf(var + 1e-5f) * gamma[0];
  float bias  = beta[0] - mean * scale;
#pragma unroll
  for (int i = 0; i < 4; ++i) {
    int idx = base + i * 256;
    float u = bilin(s, idx);
    float x = u * scale + bias;
    out[idx] = 1.f / (1.f + __expf(-x));
  }
}

// ---------------------------------------------------------------------------
extern "C" void kernel_launch(void* const* d_in, const int* in_sizes, int n_in,
                              void* d_out, int out_size, void* d_ws, size_t ws_size,
                              hipStream_t stream) {
  const float* p2    = (const float*)d_in[0];   // (2,256,64,128)
  const float* convw = (const float*)d_in[1];   // (256,256,1,9)
  const float* conv1 = (const float*)d_in[2];   // (1,256,1,1)
  const float* gamma = (const float*)d_in[3];   // (1,)
  const float* beta  = (const float*)d_in[4];   // (1,)
  float* out = (float*)d_out;                   // (2,1,256,512) fp32

  char* ws = (char*)d_ws;
  float*    s     = (float*)ws;                 // 16384 floats  [0, 64KB)
  float*    stats = (float*)(ws + 65536);       // 2 floats

  hipLaunchKernelGGL(k_scan,  dim3(64),  dim3(512), 0, stream, p2, convw, conv1, s, stats);
  hipLaunchKernelGGL(k_stats, dim3(256), dim3(256), 0, stream, s, stats);
  hipLaunchKernelGGL(k_norm,  dim3(256), dim3(256), 0, stream, s, stats, gamma, beta, out);
}

// Round 4
// 176.699 us; speedup vs baseline: 2.2991x; 2.2991x over previous
//
#include <hip/hip_runtime.h>

// ---------------------------------------------------------------------------
// R_SCNN: two width-direction SCNN scans fused into one 127-step recurrence,
// executed with MFMA, ONE barrier per step, then 4x bilinear upsample +
// global BN + sigmoid.
//
//   y_w = c_w + relu(M y_{w-1}),  z_w = y_w + relu(M z_{w-1}),  z_0 = y_0 = c_0
//   s[b,h,p] = dot(v, z_{127-p});  out = sigmoid(BN(upsample4(s)))
//
// Round-8: back to the R1 structure (8 waves x 2 tiles, raw lgkm-only
// barrier, DPP y->z handoff, z-history + post-loop dot) with ONE fix:
// A-fragments are loaded through a VOLATILE pointer. R1's VGPR_Count=64
// proved the compiler was rematerializing all 16 A-fragment loads from
// global memory EVERY STEP; those remat loads sit behind the depth-2 c_w
// HBM prefetch in the in-order vmcnt queue, so the pre-MFMA wait drained
// ~900cy of HBM latency each step (the missing 1500cy in the chain model).
// Volatile loads cannot be rematerialized -> A stays register-resident
// (~180 VGPR, still 2 waves/SIMD under launch_bounds(512,2)).
// R3's dual-recurrence direction was abandoned: wall time = per-step
// latency (all 128 recurrences already run on their own CUs).
// ---------------------------------------------------------------------------

typedef _Float16 f16x8 __attribute__((ext_vector_type(8)));
typedef _Float16 f16x4 __attribute__((ext_vector_type(4)));
typedef float    f32x4 __attribute__((ext_vector_type(4)));

// Raw workgroup barrier: drain LDS ops only; global (vmcnt) loads stay in
// flight across it.
static __device__ __forceinline__ void sync_lds() {
  asm volatile("s_waitcnt lgkmcnt(0)" ::: "memory");
  __builtin_amdgcn_s_barrier();
  asm volatile("" ::: "memory");
}

// quad_perm(0,0,2,2): lane 2k+1 receives lane 2k's value (VALU-speed, no LDS)
static __device__ __forceinline__ float dpp_even(float v) {
  int t = __builtin_bit_cast(int, v);
  t = __builtin_amdgcn_update_dpp(t, t, 0xA0, 0xF, 0xF, false);
  return __builtin_bit_cast(float, t);
}

// ---- kernel 0: extract center tap of conv_w -> dense f16 [o][c], coalesced -
extern "C" __global__ void k_extract(const float* __restrict__ convw,
                                     _Float16* __restrict__ Md) {
  int q = blockIdx.x * 256 + threadIdx.x;   // 147456 float4s = 589824 floats
  float4 v = ((const float4*)convw)[q];
  float vv[4] = {v.x, v.y, v.z, v.w};
  int f = q * 4;
#pragma unroll
  for (int e = 0; e < 4; ++e) {
    int flat = f + e;                       // flat = idx*9 + 4  <=>  center tap
    if (flat % 9 == 4) Md[flat / 9] = (_Float16)vv[e];
  }
}

// ---- kernel 1: fused double scan via MFMA ---------------------------------
struct SM {
  _Float16 cy[2][256];     // y carry (f16), ping-pong            [byte 0)
  _Float16 pad_[32];       // 64B: shifts z rows' banks by 16 vs cy
  _Float16 zh[128 * 256];  // z history; row w = z_w (also z carry) [byte 1088)
};

extern "C" __global__ void __launch_bounds__(512, 2)
k_scan(const float* __restrict__ p2, const _Float16* __restrict__ Md,
       const float* __restrict__ conv1, float* __restrict__ sout,
       float* __restrict__ stats) {
  __shared__ SM sm;
  const int tid  = threadIdx.x;
  const int l    = tid & 63;
  const int r    = tid >> 6;        // wave 0..7
  const int col  = l & 15;          // MFMA n / A-row-within-tile index
  const int quad = l >> 4;          // MFMA k-group / C-row-group index
  const int b    = blockIdx.x >> 6;
  const int h    = blockIdx.x & 63;

  if (blockIdx.x == 0 && tid == 0) { stats[0] = 0.f; stats[1] = 0.f; }

  const bool isY   = (col == 0);    // lanes holding C column 0 (y results)
  const bool isZ   = (col == 1);    // lanes holding C column 1 (z results)
  const bool zlane = (l & 1);       // odd cols read the z stream as B

  // C/D rows owned by this lane: m0..m0+3 (tile 0), m1..m1+3 (tile 1)
  const int m0 = (r * 2 + 0) * 16 + quad * 4;
  const int m1 = (r * 2 + 1) * 16 + quad * 4;

  // A-fragments (M matrix): lane holds A[m = t*16+col][k = ch*32+quad*8+j].
  // VOLATILE loads: cannot be rematerialized -> forced register-resident for
  // the whole scan (R1 asm evidence: compiler was re-loading these from
  // global every step, serialized behind the HBM c-prefetch in vmcnt order).
  f16x8 A0[8], A1[8];
#pragma unroll
  for (int ch = 0; ch < 8; ++ch) {
    A0[ch] = *(const volatile f16x8*)(Md + ((r*2+0)*16 + col) * 256 + ch*32 + quad*8);
    A1[ch] = *(const volatile f16x8*)(Md + ((r*2+1)*16 + col) * 256 + ch*32 + quad*8);
  }

  // p2_r[b][c][h][w]: channel c at pbase + c*8192 + w
  const float* pbase = p2 + (size_t)b * 2097152 + (size_t)h * 128;

  // init: w=0 state (z_0 = y_0 = c_0) into cy[0] and zh row 0
  if (isY) {
    float c0a[4], c0b[4];
#pragma unroll
    for (int i = 0; i < 4; ++i) {
      c0a[i] = pbase[(size_t)(m0 + i) * 8192];
      c0b[i] = pbase[(size_t)(m1 + i) * 8192];
    }
    f16x4 pa, pb;
#pragma unroll
    for (int i = 0; i < 4; ++i) { pa[i] = (_Float16)c0a[i]; pb[i] = (_Float16)c0b[i]; }
    *(f16x4*)(sm.cy[0] + m0) = pa; *(f16x4*)(sm.cy[0] + m1) = pb;
    *(f16x4*)(sm.zh    + m0) = pa; *(f16x4*)(sm.zh    + m1) = pb;
  }

  // depth-2 c_w register pipeline (isY lanes): cca/ccb = c_w for odd steps,
  // cna/cnb for even steps; each half reloads its own set for w+2. Loads
  // stay in flight across the raw barrier.
  float cca[4], ccb[4], cna[4], cnb[4];
  if (isY) {
#pragma unroll
    for (int i = 0; i < 4; ++i) {
      cca[i] = pbase[(size_t)(m0 + i) * 8192 + 1];
      ccb[i] = pbase[(size_t)(m1 + i) * 8192 + 1];
      cna[i] = pbase[(size_t)(m0 + i) * 8192 + 2];
      cnb[i] = pbase[(size_t)(m1 + i) * 8192 + 2];
    }
  }
  sync_lds();

  // B-fragment sources: even cols read y ping-pong, odd cols read z history.
  const _Float16* pY0 = sm.cy[0] + quad * 8;   // read on odd steps
  const _Float16* pY1 = sm.cy[1] + quad * 8;   // read on even steps
  const _Float16* zrd = sm.zh + quad * 8;      // row w-1; +256/step
  _Float16*       zwr = sm.zh + 256;           // row w;   +256/step

#define STEP(W, PY, WY, CA, CB)                                                \
  do {                                                                         \
    const _Float16* bsrc = zlane ? zrd : (PY);                                 \
    f16x8 B[8];                                                                \
    _Pragma("unroll")                                                          \
    for (int ch = 0; ch < 8; ++ch)                                             \
      B[ch] = *(const f16x8*)(bsrc + ch * 32);                                 \
    f32x4 a00 = {0.f,0.f,0.f,0.f}, a01 = {0.f,0.f,0.f,0.f};                    \
    f32x4 a10 = {0.f,0.f,0.f,0.f}, a11 = {0.f,0.f,0.f,0.f};                    \
    _Pragma("unroll")                                                          \
    for (int ch = 0; ch < 4; ++ch) {                                           \
      a00 = __builtin_amdgcn_mfma_f32_16x16x32_f16(A0[ch],   B[ch],   a00,0,0,0);\
      a10 = __builtin_amdgcn_mfma_f32_16x16x32_f16(A1[ch],   B[ch],   a10,0,0,0);\
      a01 = __builtin_amdgcn_mfma_f32_16x16x32_f16(A0[ch+4], B[ch+4], a01,0,0,0);\
      a11 = __builtin_amdgcn_mfma_f32_16x16x32_f16(A1[ch+4], B[ch+4], a11,0,0,0);\
    }                                                                          \
    f32x4 acc0 = a00 + a01, acc1 = a10 + a11;                                  \
    f32x4 yf0 = {}, yf1 = {};                                                  \
    if (isY) {                                                                 \
      f16x4 yh0, yh1;                                                          \
      _Pragma("unroll")                                                        \
      for (int i = 0; i < 4; ++i) {                                            \
        yf0[i] = (CA)[i] + fmaxf(acc0[i], 0.f);                                \
        yf1[i] = (CB)[i] + fmaxf(acc1[i], 0.f);                                \
        yh0[i] = (_Float16)yf0[i]; yh1[i] = (_Float16)yf1[i];                  \
      }                                                                        \
      *(f16x4*)((WY) + m0) = yh0;                                              \
      *(f16x4*)((WY) + m1) = yh1;                                              \
      if ((W) + 2 < 128) {                                                     \
        _Pragma("unroll")                                                      \
        for (int i = 0; i < 4; ++i) {                                          \
          (CA)[i] = pbase[(size_t)(m0 + i) * 8192 + (W) + 2];                  \
          (CB)[i] = pbase[(size_t)(m1 + i) * 8192 + (W) + 2];                  \
        }                                                                      \
      }                                                                        \
    }                                                                          \
    _Pragma("unroll")                                                          \
    for (int i = 0; i < 4; ++i) {                                              \
      yf0[i] = dpp_even(yf0[i]);                                               \
      yf1[i] = dpp_even(yf1[i]);                                               \
    }                                                                          \
    if (isZ) {                                                                 \
      f16x4 zh0, zh1;                                                          \
      _Pragma("unroll")                                                        \
      for (int i = 0; i < 4; ++i) {                                            \
        zh0[i] = (_Float16)(yf0[i] + fmaxf(acc0[i], 0.f));                     \
        zh1[i] = (_Float16)(yf1[i] + fmaxf(acc1[i], 0.f));                     \
      }                                                                        \
      *(f16x4*)(zwr + m0) = zh0;                                               \
      *(f16x4*)(zwr + m1) = zh1;                                               \
    }                                                                          \
    zrd += 256; zwr += 256;                                                    \
    sync_lds();                                                                \
  } while (0)

#pragma unroll 1
  for (int w = 1; w < 127; w += 2) {
    STEP(w,     pY0, sm.cy[1], cca, ccb);  // read y buf0, write y buf1
    STEP(w + 1, pY1, sm.cy[0], cna, cnb);  // read y buf1, write y buf0
  }
  STEP(127, pY0, sm.cy[1], cca, ccb);
#undef STEP

  // s[b,h,127-w] = dot(v, z_w): 4 threads per w, 64 channels each
  {
    const int w    = tid >> 2;
    const int part = tid & 3;
    const _Float16* zr = sm.zh + w * 256 + part * 64;
    const float*    vr = conv1 + part * 64;
    float s = 0.f;
#pragma unroll
    for (int j = 0; j < 8; ++j) {
      f16x8 zv = *(const f16x8*)(zr + j * 8);
      float4 v0 = *(const float4*)(vr + j * 8);
      float4 v1 = *(const float4*)(vr + j * 8 + 4);
      s += v0.x * (float)zv[0] + v0.y * (float)zv[1]
         + v0.z * (float)zv[2] + v0.w * (float)zv[3]
         + v1.x * (float)zv[4] + v1.y * (float)zv[5]
         + v1.z * (float)zv[6] + v1.w * (float)zv[7];
    }
    s += __shfl_xor(s, 1, 64);
    s += __shfl_xor(s, 2, 64);
    if (part == 0) sout[(blockIdx.x << 7) + (127 - w)] = s;
  }
}

// ---- bilinear 4x upsample (align_corners) of s: (2,64,128) -> (2,256,512) --
static __device__ __forceinline__ float bilin(const float* __restrict__ s,
                                              int idx) {
  int bb  = idx >> 17;
  int rem = idx & 131071;
  int ho  = rem >> 9;
  int wo  = rem & 511;
  const float SY = 63.0f / 255.0f, SX = 127.0f / 511.0f;
  float fy = (float)ho * SY;
  int y0 = (int)fy; int y1 = min(y0 + 1, 63); float wy = fy - (float)y0;
  float fx = (float)wo * SX;
  int x0 = (int)fx; int x1 = min(x0 + 1, 127); float wx = fx - (float)x0;
  const float* sb = s + bb * 8192;
  float cA = sb[y0 * 128 + x0] * (1.f - wy) + sb[y1 * 128 + x0] * wy;
  float cB = sb[y0 * 128 + x1] * (1.f - wy) + sb[y1 * 128 + x1] * wy;
  return cA * (1.f - wx) + cB * wx;
}

// ---- kernel 2: global sum / sumsq of upsampled field -----------------------
extern "C" __global__ void k_stats(const float* __restrict__ s,
                                   float* __restrict__ stats) {
  int tid  = threadIdx.x;
  int base = blockIdx.x * 1024 + tid;
  float sum = 0.f, ssq = 0.f;
#pragma unroll
  for (int i = 0; i < 4; ++i) {
    float u = bilin(s, base + i * 256);
    sum += u; ssq += u * u;
  }
#pragma unroll
  for (int off = 32; off > 0; off >>= 1) {
    sum += __shfl_xor(sum, off, 64);
    ssq += __shfl_xor(ssq, off, 64);
  }
  __shared__ float ls[4], lq[4];
  int wv = tid >> 6;
  if ((tid & 63) == 0) { ls[wv] = sum; lq[wv] = ssq; }
  __syncthreads();
  if (tid == 0) {
    atomicAdd(&stats[0], ls[0] + ls[1] + ls[2] + ls[3]);
    atomicAdd(&stats[1], lq[0] + lq[1] + lq[2] + lq[3]);
  }
}

// ---- kernel 3: normalize + sigmoid -----------------------------------------
extern "C" __global__ void k_norm(const float* __restrict__ s,
                                  const float* __restrict__ stats,
                                  const float* __restrict__ gamma,
                                  const float* __restrict__ beta,
                                  float* __restrict__ out) {
  int tid  = threadIdx.x;
  int base = blockIdx.x * 1024 + tid;
  const float invN = 1.f / 262144.f;
  float mean  = stats[0] * invN;
  float var   = stats[1] * invN - mean * mean;
  float scale = rsqrtf(var + 1e-5f) * gamma[0];
  float bias  = beta[0] - mean * scale;
#pragma unroll
  for (int i = 0; i < 4; ++i) {
    int idx = base + i * 256;
    float u = bilin(s, idx);
    float x = u * scale + bias;
    out[idx] = 1.f / (1.f + __expf(-x));
  }
}

// ---------------------------------------------------------------------------
extern "C" void kernel_launch(void* const* d_in, const int* in_sizes, int n_in,
                              void* d_out, int out_size, void* d_ws, size_t ws_size,
                              hipStream_t stream) {
  const float* p2    = (const float*)d_in[0];   // (2,256,64,128)
  const float* convw = (const float*)d_in[1];   // (256,256,1,9)
  const float* conv1 = (const float*)d_in[2];   // (1,256,1,1)
  const float* gamma = (const float*)d_in[3];   // (1,)
  const float* beta  = (const float*)d_in[4];   // (1,)
  float* out = (float*)d_out;                   // (2,1,256,512) fp32

  char* ws = (char*)d_ws;
  float*    s     = (float*)ws;                 // 16384 floats  [0, 64KB)
  float*    stats = (float*)(ws + 65536);       // 2 floats
  _Float16* Md    = (_Float16*)(ws + 65792);    // 65536 f16 (128 KB)

  hipLaunchKernelGGL(k_extract, dim3(576), dim3(256), 0, stream, convw, Md);
  hipLaunchKernelGGL(k_scan,    dim3(128), dim3(512), 0, stream, p2, Md, conv1, s, stats);
  hipLaunchKernelGGL(k_stats,   dim3(256), dim3(256), 0, stream, s, stats);
  hipLaunchKernelGGL(k_norm,    dim3(256), dim3(256), 0, stream, s, stats, gamma, beta, out);
}